// Round 6
// baseline (85.863 us; speedup 1.0000x reference)
//
#include <hip/hip_runtime.h>
#include <math.h>

// Problem constants (from reference): N=50000, F=64, E=800000, C=32
#define NF 64
#define NC 32
#define BN_EPS 1e-3f

#define BSHIFT 6                // 64 receiver-nodes per bucket
#define BNODES (1 << BSHIFT)
#define NB_MAX 1024             // >= (N+63)/64 = 782
#define CAP 1280                // slots/bucket: mean ~1023, +8 sigma
#define NBIN 512                // bin role blocks
#define GSTRIDE 16              // gcnt padded: one counter per 64B line

typedef float v2f __attribute__((ext_vector_type(2)));
#define PK_FMA(acc, a, b) \
    asm("v_pk_fma_f32 %0, %1, %2, %0" : "+v"(acc) : "v"(a), "v"(b))

// ---------------------------------------------------------------------------
// Kernel 0: zero gcnt (NB_MAX*GSTRIDE ints = 64KB) via int4 stores.
// ---------------------------------------------------------------------------
__global__ __launch_bounds__(256) void zero_gcnt_kernel(int4* __restrict__ g)
{
    g[blockIdx.x * 256 + threadIdx.x] = (int4){0, 0, 0, 0};
}

// ---------------------------------------------------------------------------
// Fused kernel A. Role interleave so bin blocks are co-resident with
// transform blocks on every CU from t=0 (R5's serial-tail fix):
//   blockIdx < 2*NBIN:  odd -> bin (binIdx=blockIdx>>1), even -> transform
//   blockIdx >= 2*NBIN:  transform (tIdx = blockIdx - NBIN)
//
// Transform: y[n] = x[n]@Wb ; z[n] = x[n]@(Wt-Wb) + b.
//   thread = (channel c, 8 nodes); packed f32 FMA; weights in LDS as
//   [c][33] v2f padded rows (2-way bank alias = free).
// Bin: LDS histogram over 782 buckets -> reserve global segment (1 atomic
//   per block*bucket, line-padded counters) -> packed (nl<<16 | sender).
// ---------------------------------------------------------------------------
__global__ __launch_bounds__(256) void prep_kernel(
    const float* __restrict__ x, const float* __restrict__ W_edge,
    const float* __restrict__ b_edge,
    const int* __restrict__ senders, const int* __restrict__ receivers,
    float* __restrict__ y, float* __restrict__ z,
    int* __restrict__ gcnt, unsigned int* __restrict__ bucketData,
    int N, int E, int NB)
{
    __shared__ float S[4224];   // transform: WD[2112]+WB[2112]; bin: 2048 ints
    int t = threadIdx.x;
    int bid = (int)blockIdx.x;
    bool isBin = (bid < 2 * NBIN) && (bid & 1);

    if (!isBin) {
        // ---------------- transform ----------------
        int tIdx = (bid < 2 * NBIN) ? (bid >> 1) : (bid - NBIN);
        float* WD = S;
        float* WB = S + 2112;
        for (int i = t; i < NF * NC; i += 256) {
            int f = i >> 5, c0 = i & 31;
            float wt = W_edge[f * NC + c0];
            float wb = W_edge[(NF + f) * NC + c0];
            int d = c0 * 66 + (f >> 1) * 2 + (f & 1);   // [c][33] v2f rows
            WD[d] = wt - wb;
            WB[d] = wb;
        }
        __syncthreads();

        int c = t & 31, g = t >> 5;
        long nb0 = (long)tIdx * 64 + g * 8;
        const float4* xr[8];
#pragma unroll
        for (int j = 0; j < 8; ++j) {
            long a = nb0 + j;
            if (a > N - 1) a = N - 1;
            xr[j] = (const float4*)(x + a * NF);
        }
        const v2f* wd = (const v2f*)WD + c * 33;
        const v2f* wb = (const v2f*)WB + c * 33;
        v2f ay[8], az[8];
#pragma unroll
        for (int j = 0; j < 8; ++j) { ay[j] = (v2f){0.f, 0.f}; az[j] = (v2f){0.f, 0.f}; }
#pragma unroll
        for (int f4 = 0; f4 < 16; ++f4) {
            v2f w0d = wd[2 * f4], w1d = wd[2 * f4 + 1];
            v2f w0b = wb[2 * f4], w1b = wb[2 * f4 + 1];
#pragma unroll
            for (int j = 0; j < 8; ++j) {
                float4 xv = xr[j][f4];
                v2f xl = (v2f){xv.x, xv.y}, xh = (v2f){xv.z, xv.w};
                PK_FMA(az[j], xl, w0d); PK_FMA(ay[j], xl, w0b);
                PK_FMA(az[j], xh, w1d); PK_FMA(ay[j], xh, w1b);
            }
        }
        float be = b_edge[c];
#pragma unroll
        for (int j = 0; j < 8; ++j) {
            long n = nb0 + j;
            if (n < N) {
                y[(n << 5) + c] = ay[j].x + ay[j].y;
                z[(n << 5) + c] = az[j].x + az[j].y + be;
            }
        }
    } else {
        // ---------------- bin ----------------
        int* lcnt  = (int*)S;
        int* lbase = lcnt + NB_MAX;
        int bb = bid >> 1;
        int chunk = (E + NBIN - 1) / NBIN;
        int e0 = bb * chunk;
        int e1 = min(E, e0 + chunk);

        for (int i = t; i < NB; i += 256) lcnt[i] = 0;
        __syncthreads();
        for (int e = e0 + t; e < e1; e += 256)
            atomicAdd(&lcnt[receivers[e] >> BSHIFT], 1);
        __syncthreads();
        for (int i = t; i < NB; i += 256) {
            int cc = lcnt[i];
            lbase[i] = cc ? atomicAdd(&gcnt[i * GSTRIDE], cc) : 0;
            lcnt[i] = 0;
        }
        __syncthreads();
        for (int e = e0 + t; e < e1; e += 256) {
            int r = receivers[e];
            unsigned int s = (unsigned int)senders[e];   // N < 65536 -> 16 bits
            int bkt = r >> BSHIFT;
            int pos = lbase[bkt] + atomicAdd(&lcnt[bkt], 1);
            if (pos < CAP)
                bucketData[(long)bkt * CAP + pos] =
                    ((unsigned int)(r & (BNODES - 1)) << 16) | s;
        }
    }
}

// ---------------------------------------------------------------------------
// Kernel B: per-bucket counting-sort (LDS) -> register gather-sum -> BN ->
// head -> sigmoid.  512 threads = 16 groups x 32 lanes; 4 nodes per group.
// No accumulation atomics.
// ---------------------------------------------------------------------------
__global__ __launch_bounds__(512) void aggregate_finalize_kernel(
    const int* __restrict__ gcnt, const unsigned int* __restrict__ bucketData,
    const float* __restrict__ y, const float* __restrict__ z,
    const float* __restrict__ gamma, const float* __restrict__ beta,
    const float* __restrict__ mean, const float* __restrict__ var,
    const float* __restrict__ W1, const float* __restrict__ b1,
    const float* __restrict__ W2, const float* __restrict__ b2,
    float* __restrict__ out, int N)
{
    __shared__ unsigned short srec[CAP];   // sorted senders (16-bit)
    __shared__ int   cnt64[BNODES];        // histogram, then cursor
    __shared__ int   off[BNODES + 1];
    __shared__ float hL[BNODES * (NC + 1)];
    __shared__ float redL[BNODES][17];
    __shared__ float w1s[NC * 16];
    __shared__ float scale_s[NC], shift_s[NC], w2s[16], b1s[16];

    int t = threadIdx.x;
    if (t < NC) {
        float sc = gamma[t] * rsqrtf(var[t] + BN_EPS);
        scale_s[t] = sc;
        shift_s[t] = beta[t] - mean[t] * sc;
    }
    for (int i = t; i < NC * 16; i += 512) w1s[i] = W1[i];
    if (t >= 64 && t < 80) { w2s[t - 64] = W2[t - 64]; b1s[t - 64] = b1[t - 64]; }
    if (t < BNODES) cnt64[t] = 0;
    __syncthreads();

    int b = blockIdx.x;
    int cnt = min(gcnt[b * GSTRIDE], CAP);
    const unsigned int* rec = bucketData + (long)b * CAP;

    // histogram over 64 local keys
    for (int k = t; k < cnt; k += 512)
        atomicAdd(&cnt64[rec[k] >> 16], 1);
    __syncthreads();

    // exclusive scan (single wave64: threads 0..63)
    if (t < BNODES) {
        int v = cnt64[t];
        int incl = v;
#pragma unroll
        for (int d = 1; d < 64; d <<= 1) {
            int u = __shfl_up(incl, d);
            if ((t & 63) >= d) incl += u;
        }
        off[t] = incl - v;
        cnt64[t] = incl - v;            // cursor
        if (t == BNODES - 1) off[BNODES] = incl;
    }
    __syncthreads();

    // scatter into sorted order (one LDS atomic per record)
    for (int k = t; k < cnt; k += 512) {
        unsigned int rv = rec[k];
        int nl = (int)(rv >> 16);
        int pos = atomicAdd(&cnt64[nl], 1);
        srec[pos] = (unsigned short)(rv & 0xFFFFu);
    }
    __syncthreads();

    // gather-sum in registers: group g handles nodes 4g..4g+3, 4-wide unroll
    long n0 = (long)b << BSHIFT;
    int g = t >> 5, c = t & 31;
    const float* yc = y + c;
#pragma unroll
    for (int j = 0; j < 4; ++j) {
        int nl = (g << 2) | j;
        int o0 = off[nl], o1 = off[nl + 1];
        float acc = 0.f;
        int k = o0;
        for (; k + 4 <= o1; k += 4) {
            int s0 = srec[k], s1 = srec[k + 1], s2 = srec[k + 2], s3 = srec[k + 3];
            float a0 = yc[s0 << 5];
            float a1 = yc[s1 << 5];
            float a2 = yc[s2 << 5];
            float a3 = yc[s3 << 5];
            acc += (a0 + a1) + (a2 + a3);
        }
        for (; k < o1; ++k) acc += yc[(int)srec[k] << 5];
        float hb = 0.f;
        long n = n0 + nl;
        if (n < N) {
            float h = (float)(o1 - o0) * z[(n << 5) + c] + acc;
            hb = fmaf(h, scale_s[c], shift_s[c]);
        }
        hL[nl * (NC + 1) + c] = hb;
    }
    __syncthreads();

    // head: 64 nodes x 16 hidden = 1024 items over 512 threads
    for (int i = t; i < BNODES * 16; i += 512) {
        int nd = i >> 4, k = i & 15;
        float a = b1s[k];
#pragma unroll
        for (int cc = 0; cc < NC; ++cc)
            a = fmaf(hL[nd * (NC + 1) + cc], w1s[cc * 16 + k], a);
        redL[nd][k] = fmaxf(a, 0.f) * w2s[k];
    }
    __syncthreads();

    if (t < BNODES) {
        long n = n0 + t;
        if (n < N) {
            float o = b2[0];
#pragma unroll
            for (int k = 0; k < 16; ++k) o += redL[t][k];
            out[n] = 1.f / (1.f + expf(-o));
        }
    }
}

// ---------------------------------------------------------------------------
extern "C" void kernel_launch(void* const* d_in, const int* in_sizes, int n_in,
                              void* d_out, int out_size, void* d_ws, size_t ws_size,
                              hipStream_t stream)
{
    const float* x         = (const float*)d_in[0];
    const int*   senders   = (const int*)  d_in[1];
    const int*   receivers = (const int*)  d_in[2];
    const float* W_edge    = (const float*)d_in[3];
    const float* b_edge    = (const float*)d_in[4];
    const float* gamma     = (const float*)d_in[5];
    const float* beta      = (const float*)d_in[6];
    const float* mov_mean  = (const float*)d_in[7];
    const float* mov_var   = (const float*)d_in[8];
    const float* W1        = (const float*)d_in[9];
    const float* b1        = (const float*)d_in[10];
    const float* W2        = (const float*)d_in[11];
    const float* b2        = (const float*)d_in[12];
    float* out = (float*)d_out;

    const int N = in_sizes[0] / NF;   // 50000
    const int E = in_sizes[1];        // 800000
    const int NB = (N + BNODES - 1) >> BSHIFT;   // 782
    const int TB = NB;                           // 64 nodes per transform block

    // ws layout: y[N*32]f | z[N*32]f | gcnt[NB_MAX*GSTRIDE]i | bucketData
    float* y          = (float*)d_ws;
    float* z          = y + (long)N * NC;
    int*   gcnt       = (int*)(z + (long)N * NC);
    unsigned int* bucketData = (unsigned int*)(gcnt + NB_MAX * GSTRIDE);

    zero_gcnt_kernel<<<NB_MAX * GSTRIDE / 1024, 256, 0, stream>>>((int4*)gcnt);

    prep_kernel<<<TB + NBIN, 256, 0, stream>>>(
        x, W_edge, b_edge, senders, receivers, y, z, gcnt, bucketData,
        N, E, NB);

    aggregate_finalize_kernel<<<NB, 512, 0, stream>>>(
        gcnt, bucketData, y, z, gamma, beta, mov_mean, mov_var,
        W1, b1, W2, b2, out, N);
}

// Round 7
// 55.059 us; speedup vs baseline: 1.5595x; 1.5595x over previous
//
#include <hip/hip_runtime.h>
#include <math.h>

// Problem constants (from reference): N=50000, F=64, E=800000, C=32
#define NF 64
#define NC 32
#define BN_EPS 1e-3f

#define BSHIFT 6                 // 64 receiver-nodes per bucket
#define BNODES 64
#define NBP 800                  // padded bucket count (>= 782)
#define NBIN 512                 // bin blocks
#define EPT 7                    // edges per thread in bin (7*256=1792 >= 1563)
#define CHUNK_STRIDE 1600        // u32 slots per bin chunk (>= ceil(E/NBIN)=1563)
#define CAPR 1408                // max records per bucket (mean 1023, +12 sigma)

typedef float v2f __attribute__((ext_vector_type(2)));
#define PK_FMA(acc, a, b) \
    asm("v_pk_fma_f32 %0, %1, %2, %0" : "+v"(acc) : "v"(a), "v"(b))

// ---------------------------------------------------------------------------
// Fused kernel A. blockIdx [0,NBIN) = bin, [NBIN, NBIN+TB) = transform.
// (All blocks co-resident; roles just share the machine.)
//
// Transform (4 nodes/thread, R5 structure): y[n]=x[n]@Wb ; z[n]=x[n]@(Wt-Wb)+b
// Bin (new): single pass over chunk -> register stash -> LDS histogram over
//   782 buckets -> LDS scan -> LDS staging sorted by bucket -> coalesced
//   global flush + packed (start<<16|count) descriptor row. No global atomics,
//   no second edge pass, all stores coalesced.
// ---------------------------------------------------------------------------
__global__ __launch_bounds__(256) void prep_kernel(
    const float* __restrict__ x, const float* __restrict__ W_edge,
    const float* __restrict__ b_edge,
    const int* __restrict__ senders, const int* __restrict__ receivers,
    float* __restrict__ y, float* __restrict__ z,
    unsigned int* __restrict__ table, unsigned int* __restrict__ bucketData,
    int N, int E, int NB)
{
    __shared__ unsigned int S[4224];   // transform: 4224 floats; bin: 3200 u32
    int t = threadIdx.x;
    int bid = (int)blockIdx.x;

    if (bid < NBIN) {
        // ---------------- bin ----------------
        int* lcnt   = (int*)S;              // [NBP] histogram, then cursor
        int* lstart = (int*)S + NBP;        // [NBP] exclusive start
        unsigned int* stag = S + 2 * NBP;   // [CHUNK_STRIDE] sorted records

        int chunk = (E + NBIN - 1) / NBIN;  // 1563
        int e0 = bid * chunk;
        int e1 = min(E, e0 + chunk);
        int nrec = e1 - e0;

        for (int i = t; i < NBP; i += 256) lcnt[i] = 0;
        __syncthreads();

        // single global pass: stash records in registers + LDS histogram
        unsigned int recs[EPT];
#pragma unroll
        for (int i = 0; i < EPT; ++i) {
            int e = e0 + t + i * 256;
            if (e < e1) {
                unsigned int r = (unsigned int)receivers[e];
                unsigned int s = (unsigned int)senders[e];   // < 65536
                recs[i] = (r << 16) | s;
                atomicAdd(&lcnt[r >> BSHIFT], 1);
            } else {
                recs[i] = 0xFFFFFFFFu;      // r=0xFFFF impossible (N<65536)
            }
        }
        __syncthreads();

        // exclusive scan of lcnt[0..NBP) -> lstart  (4 elems/thread serial +
        // wave scan + cross-wave)
        {
            int i0 = t * 4;
            int a0 = (i0 + 0 < NBP) ? lcnt[i0 + 0] : 0;
            int a1 = (i0 + 1 < NBP) ? lcnt[i0 + 1] : 0;
            int a2 = (i0 + 2 < NBP) ? lcnt[i0 + 2] : 0;
            int a3 = (i0 + 3 < NBP) ? lcnt[i0 + 3] : 0;
            int tsum = a0 + a1 + a2 + a3;
            int lane = t & 63, w = t >> 6;
            int incl = tsum;
#pragma unroll
            for (int d = 1; d < 64; d <<= 1) {
                int u = __shfl_up(incl, d);
                if (lane >= d) incl += u;
            }
            __shared__ int wsum[4];
            if (lane == 63) wsum[w] = incl;
            __syncthreads();
            int base = 0;
            for (int j = 0; j < w; ++j) base += wsum[j];
            int excl = base + incl - tsum;
            if (i0 + 0 < NBP) lstart[i0 + 0] = excl;
            if (i0 + 1 < NBP) lstart[i0 + 1] = excl + a0;
            if (i0 + 2 < NBP) lstart[i0 + 2] = excl + a0 + a1;
            if (i0 + 3 < NBP) lstart[i0 + 3] = excl + a0 + a1 + a2;
        }
        __syncthreads();
        // cursor = copy of lstart (reuse lcnt)
        for (int i = t; i < NBP; i += 256) lcnt[i] = lstart[i];
        __syncthreads();

        // place records into staging, sorted by bucket
#pragma unroll
        for (int i = 0; i < EPT; ++i) {
            unsigned int rec = recs[i];
            if (rec != 0xFFFFFFFFu) {
                int bkt = (int)(rec >> 22);                  // r >> 6
                int pos = atomicAdd(&lcnt[bkt], 1);
                stag[pos] = (((rec >> 16) & 63u) << 16) | (rec & 0xFFFFu);
            }
        }
        __syncthreads();

        // coalesced flush + descriptor row
        unsigned int* dstC = bucketData + (long)bid * CHUNK_STRIDE;
        for (int i = t; i < nrec; i += 256) dstC[i] = stag[i];
        unsigned int* dstT = table + (long)bid * NBP;
        for (int i = t; i < NB; i += 256) {
            int st = lstart[i];
            dstT[i] = ((unsigned int)st << 16) | (unsigned int)(lcnt[i] - st);
        }
    } else {
        // ---------------- transform (R5 4-node structure) ----------------
        int tIdx = bid - NBIN;
        float* WD = (float*)S;
        float* WB = (float*)S + 2112;
        for (int i = t; i < NF * NC; i += 256) {
            int f = i >> 5, c0 = i & 31;
            float wt = W_edge[i];
            float wb = W_edge[NF * NC + i];
            int d = c0 * 66 + (f >> 1) * 2 + (f & 1);   // [c][33] v2f rows
            WD[d] = wt - wb;
            WB[d] = wb;
        }
        __syncthreads();

        int c = t & 31, g = t >> 5;
        long nb0 = (long)tIdx * 32 + g * 4;
        const float4* xr0; const float4* xr1; const float4* xr2; const float4* xr3;
        {
            long m = N - 1;
            long a0 = nb0 + 0 > m ? m : nb0 + 0;
            long a1 = nb0 + 1 > m ? m : nb0 + 1;
            long a2 = nb0 + 2 > m ? m : nb0 + 2;
            long a3 = nb0 + 3 > m ? m : nb0 + 3;
            xr0 = (const float4*)(x + a0 * NF);
            xr1 = (const float4*)(x + a1 * NF);
            xr2 = (const float4*)(x + a2 * NF);
            xr3 = (const float4*)(x + a3 * NF);
        }
        const v2f* wd = (const v2f*)WD + c * 33;
        const v2f* wb = (const v2f*)WB + c * 33;
        v2f ay0 = {0.f,0.f}, ay1 = {0.f,0.f}, ay2 = {0.f,0.f}, ay3 = {0.f,0.f};
        v2f az0 = {0.f,0.f}, az1 = {0.f,0.f}, az2 = {0.f,0.f}, az3 = {0.f,0.f};
#pragma unroll
        for (int f4 = 0; f4 < 16; ++f4) {
            float4 x0 = xr0[f4], x1 = xr1[f4], x2 = xr2[f4], x3 = xr3[f4];
            v2f w0d = wd[2 * f4], w1d = wd[2 * f4 + 1];
            v2f w0b = wb[2 * f4], w1b = wb[2 * f4 + 1];
            v2f xl, xh;
            xl = (v2f){x0.x, x0.y}; xh = (v2f){x0.z, x0.w};
            PK_FMA(az0, xl, w0d); PK_FMA(ay0, xl, w0b);
            PK_FMA(az0, xh, w1d); PK_FMA(ay0, xh, w1b);
            xl = (v2f){x1.x, x1.y}; xh = (v2f){x1.z, x1.w};
            PK_FMA(az1, xl, w0d); PK_FMA(ay1, xl, w0b);
            PK_FMA(az1, xh, w1d); PK_FMA(ay1, xh, w1b);
            xl = (v2f){x2.x, x2.y}; xh = (v2f){x2.z, x2.w};
            PK_FMA(az2, xl, w0d); PK_FMA(ay2, xl, w0b);
            PK_FMA(az2, xh, w1d); PK_FMA(ay2, xh, w1b);
            xl = (v2f){x3.x, x3.y}; xh = (v2f){x3.z, x3.w};
            PK_FMA(az3, xl, w0d); PK_FMA(ay3, xl, w0b);
            PK_FMA(az3, xh, w1d); PK_FMA(ay3, xh, w1b);
        }
        float be = b_edge[c];
        long n;
        n = nb0 + 0; if (n < N) { y[(n << 5) + c] = ay0.x + ay0.y; z[(n << 5) + c] = az0.x + az0.y + be; }
        n = nb0 + 1; if (n < N) { y[(n << 5) + c] = ay1.x + ay1.y; z[(n << 5) + c] = az1.x + az1.y + be; }
        n = nb0 + 2; if (n < N) { y[(n << 5) + c] = ay2.x + ay2.y; z[(n << 5) + c] = az2.x + az2.y + be; }
        n = nb0 + 3; if (n < N) { y[(n << 5) + c] = ay3.x + ay3.y; z[(n << 5) + c] = az3.x + az3.y + be; }
    }
}

// ---------------------------------------------------------------------------
// Kernel B: per-bucket. Gather records from the 512 chunk segments (descriptor
// scan + LDS copy), counting-sort by local node, register gather-sum, BN,
// head, sigmoid.  512 threads; thread t owns chunk segment t in the prologue.
// ---------------------------------------------------------------------------
__global__ __launch_bounds__(512) void aggregate_finalize_kernel(
    const unsigned int* __restrict__ table,
    const unsigned int* __restrict__ bucketData,
    const float* __restrict__ y, const float* __restrict__ z,
    const float* __restrict__ gamma, const float* __restrict__ beta,
    const float* __restrict__ mean, const float* __restrict__ var,
    const float* __restrict__ W1, const float* __restrict__ b1,
    const float* __restrict__ W2, const float* __restrict__ b2,
    float* __restrict__ out, int N)
{
    __shared__ unsigned int raw[CAPR];     // unsorted records (nl<<16 | s)
    __shared__ unsigned short srec[CAPR];  // senders sorted by nl
    __shared__ int   segsum[8];
    __shared__ int   cnt64[BNODES];        // nl histogram, then cursor
    __shared__ int   off[BNODES + 1];
    __shared__ float hL[BNODES * (NC + 1)];
    __shared__ float redL[BNODES][17];
    __shared__ float w1s[NC * 16];
    __shared__ float scale_s[NC], shift_s[NC], w2s[16], b1s[16];

    int t = threadIdx.x;
    int b = blockIdx.x;

    if (t < NC) {
        float sc = gamma[t] * rsqrtf(var[t] + BN_EPS);
        scale_s[t] = sc;
        shift_s[t] = beta[t] - mean[t] * sc;
    }
    for (int i = t; i < NC * 16; i += 512) w1s[i] = W1[i];
    if (t >= 64 && t < 80) { w2s[t - 64] = W2[t - 64]; b1s[t - 64] = b1[t - 64]; }
    if (t < BNODES) cnt64[t] = 0;

    // descriptor for my segment + 512-thread scan of counts
    unsigned int d = table[(long)t * NBP + b];
    int cntt = (int)(d & 0xFFFFu);
    int stt  = (int)(d >> 16);
    int lane = t & 63, w = t >> 6;
    int incl = cntt;
#pragma unroll
    for (int dd = 1; dd < 64; dd <<= 1) {
        int u = __shfl_up(incl, dd);
        if (lane >= dd) incl += u;
    }
    if (lane == 63) segsum[w] = incl;
    __syncthreads();
    int base = 0, tot = 0;
#pragma unroll
    for (int j = 0; j < 8; ++j) {
        int v = segsum[j];
        if (j < w) base += v;
        tot += v;
    }
    int dst = base + incl - cntt;
    if (tot > CAPR) tot = CAPR;

    // copy my segment's records into raw[]
    const unsigned int* src = bucketData + (long)t * CHUNK_STRIDE + stt;
    for (int k = 0; k < cntt; ++k) {
        int p = dst + k;
        if (p < CAPR) raw[p] = src[k];
    }
    __syncthreads();

    // histogram over local-node keys
    for (int k = t; k < tot; k += 512)
        atomicAdd(&cnt64[raw[k] >> 16], 1);
    __syncthreads();

    // exclusive scan (single wave64)
    if (t < BNODES) {
        int v = cnt64[t];
        int incl2 = v;
#pragma unroll
        for (int dd = 1; dd < 64; dd <<= 1) {
            int u = __shfl_up(incl2, dd);
            if ((t & 63) >= dd) incl2 += u;
        }
        off[t] = incl2 - v;
        cnt64[t] = incl2 - v;            // cursor
        if (t == BNODES - 1) off[BNODES] = incl2;
    }
    __syncthreads();

    // scatter into sorted order
    for (int k = t; k < tot; k += 512) {
        unsigned int rv = raw[k];
        int nl = (int)(rv >> 16);
        int pos = atomicAdd(&cnt64[nl], 1);
        srec[pos] = (unsigned short)(rv & 0xFFFFu);
    }
    __syncthreads();

    // gather-sum in registers: group g handles nodes 4g..4g+3, 4-wide unroll
    long n0 = (long)b << BSHIFT;
    int g = t >> 5, c = t & 31;
    const float* yc = y + c;
#pragma unroll
    for (int j = 0; j < 4; ++j) {
        int nl = (g << 2) | j;
        int o0 = off[nl], o1 = off[nl + 1];
        float acc = 0.f;
        int k = o0;
        for (; k + 4 <= o1; k += 4) {
            int s0 = srec[k], s1 = srec[k + 1], s2 = srec[k + 2], s3 = srec[k + 3];
            float a0 = yc[s0 << 5];
            float a1 = yc[s1 << 5];
            float a2 = yc[s2 << 5];
            float a3 = yc[s3 << 5];
            acc += (a0 + a1) + (a2 + a3);
        }
        for (; k < o1; ++k) acc += yc[(int)srec[k] << 5];
        float hb = 0.f;
        long n = n0 + nl;
        if (n < N) {
            float h = (float)(o1 - o0) * z[(n << 5) + c] + acc;
            hb = fmaf(h, scale_s[c], shift_s[c]);
        }
        hL[nl * (NC + 1) + c] = hb;
    }
    __syncthreads();

    // head: 64 nodes x 16 hidden = 1024 items over 512 threads
    for (int i = t; i < BNODES * 16; i += 512) {
        int nd = i >> 4, k = i & 15;
        float a = b1s[k];
#pragma unroll
        for (int cc = 0; cc < NC; ++cc)
            a = fmaf(hL[nd * (NC + 1) + cc], w1s[cc * 16 + k], a);
        redL[nd][k] = fmaxf(a, 0.f) * w2s[k];
    }
    __syncthreads();

    if (t < BNODES) {
        long n = n0 + t;
        if (n < N) {
            float o = b2[0];
#pragma unroll
            for (int k = 0; k < 16; ++k) o += redL[t][k];
            out[n] = 1.f / (1.f + expf(-o));
        }
    }
}

// ---------------------------------------------------------------------------
extern "C" void kernel_launch(void* const* d_in, const int* in_sizes, int n_in,
                              void* d_out, int out_size, void* d_ws, size_t ws_size,
                              hipStream_t stream)
{
    const float* x         = (const float*)d_in[0];
    const int*   senders   = (const int*)  d_in[1];
    const int*   receivers = (const int*)  d_in[2];
    const float* W_edge    = (const float*)d_in[3];
    const float* b_edge    = (const float*)d_in[4];
    const float* gamma     = (const float*)d_in[5];
    const float* beta      = (const float*)d_in[6];
    const float* mov_mean  = (const float*)d_in[7];
    const float* mov_var   = (const float*)d_in[8];
    const float* W1        = (const float*)d_in[9];
    const float* b1        = (const float*)d_in[10];
    const float* W2        = (const float*)d_in[11];
    const float* b2        = (const float*)d_in[12];
    float* out = (float*)d_out;

    const int N = in_sizes[0] / NF;   // 50000
    const int E = in_sizes[1];        // 800000
    const int NB = (N + BNODES - 1) >> BSHIFT;   // 782
    const int TB = (N + 31) / 32;                // 1563

    // ws layout: y[N*32]f | z[N*32]f | table[NBIN*NBP]u32 | bucketData[NBIN*1600]u32
    float* y            = (float*)d_ws;
    float* z            = y + (long)N * NC;
    unsigned int* table = (unsigned int*)(z + (long)N * NC);
    unsigned int* bucketData = table + (long)NBIN * NBP;

    prep_kernel<<<NBIN + TB, 256, 0, stream>>>(
        x, W_edge, b_edge, senders, receivers, y, z, table, bucketData,
        N, E, NB);

    aggregate_finalize_kernel<<<NB, 512, 0, stream>>>(
        table, bucketData, y, z, gamma, beta, mov_mean, mov_var,
        W1, b1, W2, b2, out, N);
}